// Round 4
// baseline (440.865 us; speedup 1.0000x reference)
//
#include <hip/hip_runtime.h>

// Emformer mask materialization — persistent-grid grid-stride version.
//
// R3 decisive evidence: hipMemsetD32Async (the SAME rocclr fillBufferAligned
// kernel that sustains 6.1 TB/s on the 1.7 GB poison fill) wrote our 424.6 MB
// output at only ~3.1 TB/s in our stream position — identical to every hand
// kernel (3.0/2.1/2.6 TB/s). The cap is contextual (424 MB vs 256 MB L3 +
// inherited dirty-line drain from the preceding poison), not our store code.
// Last unfalsified geometry lever: all our kernels used 1-store-per-thread
// with ~100k short-lived workgroups; the fast fill uses a small persistent
// grid with a grid-stride loop. This kernel = R0's proven math + fill-style
// geometry: 2048 blocks (8/CU, one scheduling round), one aligned dwordx4
// store per iteration, division-free incremental (row, col) tracking.
//
// Output int32: 1 = attention disallowed, 0 = allowed.
namespace {
constexpr int SEG  = 128;   // segment_length
constexpr int RCL  = 32;    // right_context_length
constexpr int LC   = 64;    // left_context_length
constexpr int MEM  = 4;     // max_memory_length
constexpr int NSEG = 64;    // num_segments
constexpr int U    = NSEG * SEG;                    // 8192
constexpr int W    = (NSEG - 1) + RCL * NSEG + U;   // 10303 (mask width)
constexpr int RC_ROWS = RCL * NSEG;                 // 2048
constexpr int Q_ROWS  = U;                          // 8192
constexpr int ROWS    = RC_ROWS + Q_ROWS + NSEG;    // 10304
constexpr unsigned TOTAL  = (unsigned)ROWS * (unsigned)W;  // 106,162,112
constexpr unsigned TOTAL4 = TOTAL / 4u;                    // 26,540,528 i32x4
constexpr int UTT_BASE = (NSEG - 1) + RCL * NSEG;   // 2111

constexpr int BLOCKS = 2048;                           // 8 blocks/CU, one round
constexpr unsigned NTHREADS   = (unsigned)BLOCKS * 256u;   // 524,288
constexpr unsigned STRIDE_INT = NTHREADS * 4u;             // 2,097,152 ints/iter
constexpr int R_STEP = (int)(STRIDE_INT / (unsigned)W);                     // 203
constexpr int J_STEP = (int)(STRIDE_INT - (unsigned)R_STEP * (unsigned)W);  // 5643
static_assert(J_STEP < W, "at most one extra row per stride");
}

typedef int i32x4 __attribute__((ext_vector_type(4)));

// Per-row allowed-column ranges (three half-open intervals).
__device__ __forceinline__ void row_params(int r, int& a0, int& a1, int& b0,
                                           int& b1, int& d0, int& d1) {
    int i;
    bool is_s;
    if (r < RC_ROWS) {                 // right-context query rows
        i = r >> 5;
        is_s = false;
    } else if (r < RC_ROWS + Q_ROWS) { // utterance query rows
        i = (r - RC_ROWS) >> 7;
        is_s = false;
    } else {                           // summary rows
        i = r - (RC_ROWS + Q_ROWS);
        is_s = true;
    }
    a0 = max(i - MEM, 0);
    a1 = i;
    if (is_s) { b0 = 0; b1 = 0; }
    else      { b0 = (NSEG - 1) + RCL * i; b1 = b0 + RCL; }
    d0 = UTT_BASE + max(SEG * i - LC, 0);
    d1 = UTT_BASE + SEG * (i + 1);
}

__device__ __forceinline__ int mask_at(int j, int a0, int a1, int b0, int b1,
                                       int d0, int d1) {
    bool allowed = (j >= a0 && j < a1) | (j >= b0 && j < b1) | (j >= d0 && j < d1);
    return allowed ? 0 : 1;
}

__global__ __launch_bounds__(256) void emformer_mask_kernel(i32x4* __restrict__ out) {
    unsigned q = blockIdx.x * 256u + threadIdx.x;   // i32x4 index
    if (q >= TOTAL4) return;
    unsigned f = q * 4u;                            // flat int index
    unsigned r = f / (unsigned)W;                   // one magic-div at entry
    int j = (int)(f - r * (unsigned)W);

    for (; q < TOTAL4; q += NTHREADS) {
        i32x4 v;
        if (j + 3 < W) {
            // Fast path: all 4 elements in one row.
            int a0, a1, b0, b1, d0, d1;
            row_params((int)r, a0, a1, b0, b1, d0, d1);
            v.x = mask_at(j,     a0, a1, b0, b1, d0, d1);
            v.y = mask_at(j + 1, a0, a1, b0, b1, d0, d1);
            v.z = mask_at(j + 2, a0, a1, b0, b1, d0, d1);
            v.w = mask_at(j + 3, a0, a1, b0, b1, d0, d1);
        } else {
            // Row-boundary wrap: per-element recompute.
#pragma unroll
            for (int k = 0; k < 4; ++k) {
                int jj = j + k;
                int rr = (int)r;
                if (jj >= W) { jj -= W; rr += 1; }
                int a0, a1, b0, b1, d0, d1;
                row_params(rr, a0, a1, b0, b1, d0, d1);
                v[k] = mask_at(jj, a0, a1, b0, b1, d0, d1);
            }
        }
        out[q] = v;   // plain store: aggregate dirty lines in L2/L3

        // Division-free advance to next stride position.
        j += J_STEP;
        r += (unsigned)R_STEP;
        if (j >= W) { j -= W; r += 1u; }
    }
}

extern "C" void kernel_launch(void* const* d_in, const int* in_sizes, int n_in,
                              void* d_out, int out_size, void* d_ws, size_t ws_size,
                              hipStream_t stream) {
    (void)d_in; (void)in_sizes; (void)n_in; (void)d_ws; (void)ws_size; (void)out_size;
    emformer_mask_kernel<<<dim3(BLOCKS), dim3(256), 0, stream>>>((i32x4*)d_out);
}

// Round 5
// 414.843 us; speedup vs baseline: 1.0627x; 1.0627x over previous
//
#include <hip/hip_runtime.h>

// Emformer mask materialization — FINAL: revert to the measured-best R0 kernel.
//
// Session ladder (kernel-stage time = total minus the ~275 us harness poison):
//   R0 one-shot flat dwordx4 grid ........ 141 us (3.0 TB/s)  <- best
//   R1 block-tiled 4B replicate .......... 200 us (2.1 TB/s)
//   R2 LDS byte-image + dwordx4 .......... 165 us (2.6 TB/s)
//   R3 hipMemsetD32Async + sparse carve .. 148 us (~3.1 TB/s)
//   R4 persistent 2048-block grid-stride . 165 us (2.6 TB/s)
// Controlling evidence (R3): rocclr's own fillBufferAligned — which sustains
// 6.2 TB/s on the 1.7 GB poison in the SAME timed graph — also writes this
// buffer at only ~3.1 TB/s in our stream position. The ~3 TB/s cap is
// contextual (inherited dirty-line drain of the preceding 1.7 GB poison),
// not addressable by store geometry, ALU reduction, or the vendor fill path.
//
// Output dtype int32: 1 = disallowed, 0 = allowed.
namespace {
constexpr int SEG  = 128;   // segment_length
constexpr int RCL  = 32;    // right_context_length
constexpr int LC   = 64;    // left_context_length
constexpr int MEM  = 4;     // max_memory_length
constexpr int NSEG = 64;    // num_segments
constexpr int U    = NSEG * SEG;                    // 8192
constexpr int W    = (NSEG - 1) + RCL * NSEG + U;   // 10303 (mask width)
constexpr int RC_ROWS = RCL * NSEG;                 // 2048
constexpr int Q_ROWS  = U;                          // 8192
constexpr int ROWS    = RC_ROWS + Q_ROWS + NSEG;    // 10304
constexpr unsigned TOTAL  = (unsigned)ROWS * (unsigned)W;  // 106,162,112 (div by 4)
constexpr unsigned TOTAL4 = TOTAL / 4u;                    // 26,540,528 int4s
constexpr int UTT_BASE = (NSEG - 1) + RCL * NSEG;   // 2111 (start of utterance cols)
}

typedef int i32x4 __attribute__((ext_vector_type(4)));

// Per-row allowed-column ranges. Three half-open intervals:
//   [a0,a1): memory slots (group 1)
//   [b0,b1): own right-context block (group 4) — empty for summary rows
//   [d0,d1): own segment + left context (group 7)
__device__ __forceinline__ void row_params(int r, int& a0, int& a1, int& b0,
                                           int& b1, int& d0, int& d1) {
    int i;
    bool is_s;
    if (r < RC_ROWS) {                 // right-context query rows: RC per segment
        i = r >> 5;                    // r / RCL
        is_s = false;
    } else if (r < RC_ROWS + Q_ROWS) { // utterance query rows: SEG per segment
        i = (r - RC_ROWS) >> 7;        // / SEG
        is_s = false;
    } else {                           // summary rows: 1 per segment
        i = r - (RC_ROWS + Q_ROWS);
        is_s = true;
    }
    a0 = max(i - MEM, 0);
    a1 = i;
    if (is_s) { b0 = 0; b1 = 0; }      // summary rows don't attend RC block
    else      { b0 = (NSEG - 1) + RCL * i; b1 = b0 + RCL; }
    d0 = UTT_BASE + max(SEG * i - LC, 0);
    d1 = UTT_BASE + SEG * (i + 1);
}

__device__ __forceinline__ int mask_at(int j, int a0, int a1, int b0, int b1,
                                       int d0, int d1) {
    // allowed -> mask=1 -> logical_not -> output 0; else 1
    bool allowed = (j >= a0 && j < a1) | (j >= b0 && j < b1) | (j >= d0 && j < d1);
    return allowed ? 0 : 1;
}

__global__ __launch_bounds__(256) void emformer_mask_kernel(i32x4* __restrict__ out) {
    unsigned t = blockIdx.x * 256u + threadIdx.x;
    if (t >= TOTAL4) return;
    unsigned f = t * 4u;                 // flat element index (fits in u32)
    unsigned r = f / (unsigned)W;        // constant divisor -> magic mul
    int j = (int)(f - r * (unsigned)W);

    i32x4 v;
    if (j + 3 < W) {
        // Fast path: all 4 elements in the same row — compute ranges once.
        int a0, a1, b0, b1, d0, d1;
        row_params((int)r, a0, a1, b0, b1, d0, d1);
        v.x = mask_at(j,     a0, a1, b0, b1, d0, d1);
        v.y = mask_at(j + 1, a0, a1, b0, b1, d0, d1);
        v.z = mask_at(j + 2, a0, a1, b0, b1, d0, d1);
        v.w = mask_at(j + 3, a0, a1, b0, b1, d0, d1);
    } else {
        // Row-boundary wrap (~1/2576 threads): per-element row recompute.
#pragma unroll
        for (int k = 0; k < 4; ++k) {
            int jj = j + k;
            int rr = (int)r;
            if (jj >= W) { jj -= W; rr += 1; }
            int a0, a1, b0, b1, d0, d1;
            row_params(rr, a0, a1, b0, b1, d0, d1);
            v[k] = mask_at(jj, a0, a1, b0, b1, d0, d1);
        }
    }
    // Plain store: let dirty lines aggregate in L2 and write back in bulk.
    // (Earlier session: __builtin_nontemporal_store cost ~6x write BW here.)
    out[t] = v;
}

extern "C" void kernel_launch(void* const* d_in, const int* in_sizes, int n_in,
                              void* d_out, int out_size, void* d_ws, size_t ws_size,
                              hipStream_t stream) {
    (void)d_in; (void)in_sizes; (void)n_in; (void)d_ws; (void)ws_size; (void)out_size;
    i32x4* out = (i32x4*)d_out;
    const unsigned blocks = (TOTAL4 + 255u) / 256u;
    emformer_mask_kernel<<<dim3(blocks), dim3(256), 0, stream>>>(out);
}